// Round 6
// baseline (1701.260 us; speedup 1.0000x reference)
//
#include <hip/hip_runtime.h>
#include <hip/hip_bf16.h>
#include <cstdint>
#include <cstddef>

// Problem constants: N=32768, D=2048, H=4096, E=8, T = N/E = 4096.
#define NTOK 32768
#define DDIM 2048
#define HDIM 4096
#define NEXP 8
#define TTOK 4096

typedef __attribute__((ext_vector_type(8))) __bf16 bf16x8;
typedef __attribute__((ext_vector_type(4))) float f32x4;

#define MFMA_BF16(a, b, c) __builtin_amdgcn_mfma_f32_16x16x32_bf16((a), (b), (c), 0, 0, 0)
#define SBAR() __builtin_amdgcn_s_barrier()
#define SCHED0() __builtin_amdgcn_sched_barrier(0)
#define WAIT_VM8() asm volatile("s_waitcnt vmcnt(8)" ::: "memory")
#define WAIT_VM0() asm volatile("s_waitcnt vmcnt(0)" ::: "memory")
#define WAIT_LGKM0() asm volatile("s_waitcnt lgkmcnt(0)" ::: "memory")

__device__ __forceinline__ unsigned short f2bf(float f) {
  unsigned int u = __builtin_bit_cast(unsigned int, f);
  u += 0x7FFFu + ((u >> 16) & 1u);   // round-to-nearest-even
  return (unsigned short)(u >> 16);
}

// ---------------- f32 -> bf16 convert (vectorized, grid-stride) ----------------
__global__ __launch_bounds__(256) void cvt_kernel(const float* __restrict__ src,
                                                  unsigned short* __restrict__ dst,
                                                  long n4) {
  long i = (long)blockIdx.x * blockDim.x + threadIdx.x;
  long stride = (long)gridDim.x * blockDim.x;
  const float4* s4 = (const float4*)src;
  ushort4* d4 = (ushort4*)dst;
  for (; i < n4; i += stride) {
    float4 v = s4[i];
    ushort4 o;
    o.x = f2bf(v.x); o.y = f2bf(v.y); o.z = f2bf(v.z); o.w = f2bf(v.w);
    d4[i] = o;
  }
}

// ------------- transpose w_down (E,H,D) f32 -> (E,D,H) bf16 -------------
__global__ __launch_bounds__(256) void transpose_wd(const float* __restrict__ w,
                                                    unsigned short* __restrict__ wt) {
  __shared__ unsigned short tile[64][66];
  const int e = blockIdx.z;
  const int h0 = blockIdx.y * 64;
  const int d0 = blockIdx.x * 64;
  const float* we = w + (size_t)e * HDIM * DDIM;
  unsigned short* wte = wt + (size_t)e * DDIM * HDIM;
  const int t = threadIdx.x;
  const int r = t >> 4;
  const int c4 = (t & 15) * 4;
#pragma unroll
  for (int p = 0; p < 4; ++p) {
    int h = r + p * 16;
    float4 v = *(const float4*)(we + (size_t)(h0 + h) * DDIM + d0 + c4);
    tile[h][c4 + 0] = f2bf(v.x);
    tile[h][c4 + 1] = f2bf(v.y);
    tile[h][c4 + 2] = f2bf(v.z);
    tile[h][c4 + 3] = f2bf(v.w);
  }
  __syncthreads();
#pragma unroll
  for (int p = 0; p < 4; ++p) {
    int d = r + p * 16;
    ushort4 o;
    o.x = tile[c4 + 0][d];
    o.y = tile[c4 + 1][d];
    o.z = tile[c4 + 2][d];
    o.w = tile[c4 + 3][d];
    *(ushort4*)(wte + (size_t)(d0 + d) * HDIM + h0 + c4) = o;
  }
}

// ------------- staging: half-tile = 128 rows x 64 bf16, 512 threads x 2 loads -------------
// LDS dest linear; swizzle via inverse-XOR on the GLOBAL source granule (rule #21).
// Proven 0 bank conflicts (rounds 1-5).
__device__ __forceinline__ void stage_half(const unsigned short* __restrict__ g0,
                                           size_t stride_elems,
                                           unsigned short* lds, int tid) {
#pragma unroll
  for (int i = 0; i < 2; ++i) {
    int gi = i * 512 + tid;          // granule 0..1023 (16B); r=row 0..127, c=granule 0..7
    int r = gi >> 3;
    int c = gi & 7;
    const unsigned short* src = g0 + (size_t)r * stride_elems + ((c ^ (r & 7)) << 3);
    __builtin_amdgcn_global_load_lds(
        (const __attribute__((address_space(1))) unsigned int*)src,
        (__attribute__((address_space(3))) unsigned int*)(lds + (size_t)gi * 8),
        16, 0, 0);
  }
}

__device__ __forceinline__ bf16x8 read_frag(const unsigned short* lds, int row, int cg) {
  return *(const bf16x8*)(lds + row * 64 + ((cg ^ (row & 7)) << 3));
}

// ------------- GEMM1 + SwiGLU: 256-tok x 128-h tile, 3-phase read-ahead pipeline -------------
// A tile 256x64 (x); B tile 256x64 = [up 128 ; gate 128]. 8 waves = 2M x 4N;
// wave owns 128 tok x 32 h for BOTH up and gate (acc 32 f32x4).
// P1: read a0,bu,bg + MFMA(m0*u) | P2: read a1 + stage B(t+2) + MFMA(m0*g) |
// P3: stage A(t+2) + MFMA(m1*u)+(m1*g).  vmcnt(8) once per tile.
__global__ __launch_bounds__(512, 2) void gemm1_swiglu(
    const unsigned short* __restrict__ Xb,
    const unsigned short* __restrict__ Wb,
    unsigned short* __restrict__ Hid) {
  __shared__ unsigned short smem[2][2][256 * 64];   // [buf][A=0,B=1]  128 KiB
  const int e = blockIdx.z;
  const int bm = blockIdx.y;   // token tile (256)
  const int bn = blockIdx.x;   // h tile (128)
  const unsigned short* Xe = Xb + ((size_t)e * TTOK + bm * 256) * DDIM;
  const unsigned short* Wu = Wb + ((size_t)e * 2 * HDIM + (size_t)bn * 128) * DDIM;
  const unsigned short* Wg = Wu + (size_t)HDIM * DDIM;
  const int tid = threadIdx.x;
  const int lane = tid & 63;
  const int wid = tid >> 6;
  const int wm = (wid & 1) * 128;   // M-half rows
  const int wn = (wid >> 1) * 32;   // h cols within 128
  const int lr = lane & 15;
  const int lk = lane >> 4;

  f32x4 au[8][2], ag[8][2];
#pragma unroll
  for (int i = 0; i < 8; ++i)
#pragma unroll
    for (int j = 0; j < 2; ++j) {
      au[i][j] = f32x4{0.f, 0.f, 0.f, 0.f};
      ag[i][j] = f32x4{0.f, 0.f, 0.f, 0.f};
    }

  auto stageA = [&](int t, int half) {
    stage_half(Xe + (size_t)(half * 128) * DDIM + t * 64, DDIM,
               (unsigned short*)smem[t & 1][0] + half * (128 * 64), tid);
  };
  auto stageB = [&](int t, int half) {   // half0 = up rows, half1 = gate rows
    stage_half((half ? Wg : Wu) + t * 64, DDIM,
               (unsigned short*)smem[t & 1][1] + half * (128 * 64), tid);
  };

  // prologue: tiles 0 and 1 (8 loads/thread each)
  stageB(0, 0); stageB(0, 1); stageA(0, 0); stageA(0, 1);
  stageB(1, 0); stageB(1, 1); stageA(1, 0); stageA(1, 1);

  const int NT = DDIM / 64;   // 32
  for (int t = 0; t < NT; ++t) {
    const unsigned short* A = smem[t & 1][0];
    const unsigned short* B = smem[t & 1][1];
    if (t + 1 < NT) { WAIT_VM8(); } else { WAIT_VM0(); }
    SBAR(); SCHED0();
    bf16x8 a0[4][2], a1[4][2], bu[2][2], bg[2][2];
    // ---- P1: read a0(8), bu(4), bg(4); MFMA (m0, up)
#pragma unroll
    for (int mi = 0; mi < 4; ++mi)
#pragma unroll
      for (int kh = 0; kh < 2; ++kh)
        a0[mi][kh] = read_frag(A, wm + mi * 16 + lr, kh * 4 + lk);
#pragma unroll
    for (int ni = 0; ni < 2; ++ni)
#pragma unroll
      for (int kh = 0; kh < 2; ++kh) {
        bu[ni][kh] = read_frag(B, wn + ni * 16 + lr, kh * 4 + lk);
        bg[ni][kh] = read_frag(B, 128 + wn + ni * 16 + lr, kh * 4 + lk);
      }
    __builtin_amdgcn_s_setprio(1);
#pragma unroll
    for (int kh = 0; kh < 2; ++kh)
#pragma unroll
      for (int mi = 0; mi < 4; ++mi)
#pragma unroll
        for (int ni = 0; ni < 2; ++ni)
          au[mi][ni] = MFMA_BF16(a0[mi][kh], bu[ni][kh], au[mi][ni]);
    __builtin_amdgcn_s_setprio(0);
    WAIT_LGKM0();
    SBAR(); SCHED0();
    // ---- P2: read a1(8); stage B0,B1(t+2); MFMA (m0, gate) [operands pre-read]
#pragma unroll
    for (int mi = 0; mi < 4; ++mi)
#pragma unroll
      for (int kh = 0; kh < 2; ++kh)
        a1[mi][kh] = read_frag(A, wm + 64 + mi * 16 + lr, kh * 4 + lk);
    if (t + 2 < NT) { stageB(t + 2, 0); stageB(t + 2, 1); }
    __builtin_amdgcn_s_setprio(1);
#pragma unroll
    for (int kh = 0; kh < 2; ++kh)
#pragma unroll
      for (int mi = 0; mi < 4; ++mi)
#pragma unroll
        for (int ni = 0; ni < 2; ++ni)
          ag[mi][ni] = MFMA_BF16(a0[mi][kh], bg[ni][kh], ag[mi][ni]);
    __builtin_amdgcn_s_setprio(0);
    WAIT_LGKM0();
    SBAR(); SCHED0();
    // ---- P3: stage A0,A1(t+2); MFMA (m1, up) + (m1, gate) [operands pre-read]
    if (t + 2 < NT) { stageA(t + 2, 0); stageA(t + 2, 1); }
    __builtin_amdgcn_s_setprio(1);
#pragma unroll
    for (int kh = 0; kh < 2; ++kh)
#pragma unroll
      for (int mi = 0; mi < 4; ++mi)
#pragma unroll
        for (int ni = 0; ni < 2; ++ni) {
          au[4 + mi][ni] = MFMA_BF16(a1[mi][kh], bu[ni][kh], au[4 + mi][ni]);
          ag[4 + mi][ni] = MFMA_BF16(a1[mi][kh], bg[ni][kh], ag[4 + mi][ni]);
        }
    __builtin_amdgcn_s_setprio(0);
    // tile-closing barrier = next iteration's top barrier
  }

  // epilogue: hidden = up * silu(gate); C layout col=lane&15, row=(lane>>4)*4+reg
  unsigned short* He = Hid + ((size_t)e * TTOK + bm * 256) * HDIM + (size_t)bn * 128;
#pragma unroll
  for (int mi = 0; mi < 8; ++mi) {
    int mrow = wm + ((mi < 4) ? mi * 16 : 64 + (mi - 4) * 16);
#pragma unroll
    for (int ni = 0; ni < 2; ++ni)
#pragma unroll
      for (int r = 0; r < 4; ++r) {
        int row = mrow + lk * 4 + r;
        int col = wn + ni * 16 + lr;
        float u = au[mi][ni][r];
        float g = ag[mi][ni][r];
        He[(size_t)row * HDIM + col] = f2bf(u * g / (1.f + __expf(-g)));
      }
  }
}

// ------------- GEMM2: out = hidden @ w_downT, 256x256 tile, 3-phase read-ahead -------------
// P1: read a0,b0,b1 + MFMA(m0,n0) | P2: read a1 + stage B(t+2) + MFMA(m0,n1) |
// P3: stage A(t+2) + MFMA(m1,n0)+(m1,n1).
__global__ __launch_bounds__(512, 2) void gemm2_down(
    const unsigned short* __restrict__ Hid,
    const unsigned short* __restrict__ WdT,
    float* __restrict__ Out) {
  __shared__ unsigned short smem[2][2][256 * 64];   // 128 KiB
  const int e = blockIdx.z;
  const int bm = blockIdx.y;   // token tile (256)
  const int bn = blockIdx.x;   // d tile (256)
  const unsigned short* Ae = Hid + ((size_t)e * TTOK + bm * 256) * HDIM;
  const unsigned short* Be = WdT + ((size_t)e * DDIM + (size_t)bn * 256) * HDIM;
  const int tid = threadIdx.x;
  const int lane = tid & 63;
  const int wid = tid >> 6;
  const int wm = (wid & 1) * 128;
  const int wn = (wid >> 1) * 64;
  const int lr = lane & 15;
  const int lk = lane >> 4;

  f32x4 acc[8][4];
#pragma unroll
  for (int i = 0; i < 8; ++i)
#pragma unroll
    for (int j = 0; j < 4; ++j) acc[i][j] = f32x4{0.f, 0.f, 0.f, 0.f};

  auto stageA = [&](int t, int half) {
    stage_half(Ae + (size_t)(half * 128) * HDIM + t * 64, HDIM,
               (unsigned short*)smem[t & 1][0] + half * (128 * 64), tid);
  };
  auto stageB = [&](int t, int half) {
    stage_half(Be + (size_t)(half * 128) * HDIM + t * 64, HDIM,
               (unsigned short*)smem[t & 1][1] + half * (128 * 64), tid);
  };

  stageB(0, 0); stageB(0, 1); stageA(0, 0); stageA(0, 1);
  stageB(1, 0); stageB(1, 1); stageA(1, 0); stageA(1, 1);

  const int NT = HDIM / 64;   // 64
  for (int t = 0; t < NT; ++t) {
    const unsigned short* A = smem[t & 1][0];
    const unsigned short* B = smem[t & 1][1];
    if (t + 1 < NT) { WAIT_VM8(); } else { WAIT_VM0(); }
    SBAR(); SCHED0();
    bf16x8 a0[4][2], a1[4][2], b0[2][2], b1[2][2];
    // ---- P1: read a0(8), b0(4), b1(4); MFMA (m0,n0)
#pragma unroll
    for (int mi = 0; mi < 4; ++mi)
#pragma unroll
      for (int kh = 0; kh < 2; ++kh)
        a0[mi][kh] = read_frag(A, wm + mi * 16 + lr, kh * 4 + lk);
#pragma unroll
    for (int ni = 0; ni < 2; ++ni)
#pragma unroll
      for (int kh = 0; kh < 2; ++kh) {
        b0[ni][kh] = read_frag(B, wn + ni * 16 + lr, kh * 4 + lk);
        b1[ni][kh] = read_frag(B, wn + 32 + ni * 16 + lr, kh * 4 + lk);
      }
    __builtin_amdgcn_s_setprio(1);
#pragma unroll
    for (int kh = 0; kh < 2; ++kh)
#pragma unroll
      for (int mi = 0; mi < 4; ++mi)
#pragma unroll
        for (int ni = 0; ni < 2; ++ni)
          acc[mi][ni] = MFMA_BF16(a0[mi][kh], b0[ni][kh], acc[mi][ni]);
    __builtin_amdgcn_s_setprio(0);
    WAIT_LGKM0();
    SBAR(); SCHED0();
    // ---- P2: read a1(8); stage B0,B1(t+2); MFMA (m0,n1)
#pragma unroll
    for (int mi = 0; mi < 4; ++mi)
#pragma unroll
      for (int kh = 0; kh < 2; ++kh)
        a1[mi][kh] = read_frag(A, wm + 64 + mi * 16 + lr, kh * 4 + lk);
    if (t + 2 < NT) { stageB(t + 2, 0); stageB(t + 2, 1); }
    __builtin_amdgcn_s_setprio(1);
#pragma unroll
    for (int kh = 0; kh < 2; ++kh)
#pragma unroll
      for (int mi = 0; mi < 4; ++mi)
#pragma unroll
        for (int ni = 0; ni < 2; ++ni)
          acc[mi][2 + ni] = MFMA_BF16(a0[mi][kh], b1[ni][kh], acc[mi][2 + ni]);
    __builtin_amdgcn_s_setprio(0);
    WAIT_LGKM0();
    SBAR(); SCHED0();
    // ---- P3: stage A0,A1(t+2); MFMA (m1,n0) + (m1,n1)
    if (t + 2 < NT) { stageA(t + 2, 0); stageA(t + 2, 1); }
    __builtin_amdgcn_s_setprio(1);
#pragma unroll
    for (int kh = 0; kh < 2; ++kh)
#pragma unroll
      for (int mi = 0; mi < 4; ++mi)
#pragma unroll
        for (int ni = 0; ni < 2; ++ni) {
          acc[4 + mi][ni] = MFMA_BF16(a1[mi][kh], b0[ni][kh], acc[4 + mi][ni]);
          acc[4 + mi][2 + ni] = MFMA_BF16(a1[mi][kh], b1[ni][kh], acc[4 + mi][2 + ni]);
        }
    __builtin_amdgcn_s_setprio(0);
  }

  float* Oe = Out + ((size_t)e * TTOK + bm * 256) * DDIM + (size_t)bn * 256;
#pragma unroll
  for (int mi = 0; mi < 8; ++mi) {
    int mrow = wm + ((mi < 4) ? mi * 16 : 64 + (mi - 4) * 16);
#pragma unroll
    for (int ni = 0; ni < 4; ++ni) {
      int col = wn + ((ni < 2) ? ni * 16 : 32 + (ni - 2) * 16) + lr;
#pragma unroll
      for (int r = 0; r < 4; ++r) {
        int row = mrow + lk * 4 + r;
        Oe[(size_t)row * DDIM + col] = acc[mi][ni][r];
      }
    }
  }
}

extern "C" void kernel_launch(void* const* d_in, const int* in_sizes, int n_in,
                              void* d_out, int out_size, void* d_ws, size_t ws_size,
                              hipStream_t stream) {
  const float* x = (const float*)d_in[0];
  const float* wug = (const float*)d_in[1];
  const float* wd = (const float*)d_in[2];
  float* out = (float*)d_out;

  unsigned short* xb   = (unsigned short*)d_ws;                    // 32768*2048
  unsigned short* wugb = xb   + (size_t)NTOK * DDIM;               // 8*8192*2048
  unsigned short* wdT  = wugb + (size_t)NEXP * 2 * HDIM * DDIM;    // 8*2048*4096
  unsigned short* hid  = wdT  + (size_t)NEXP * DDIM * HDIM;        // 8*4096*4096

  cvt_kernel<<<4096, 256, 0, stream>>>(x, xb, (long)NTOK * DDIM / 4);
  cvt_kernel<<<4096, 256, 0, stream>>>(wug, wugb, (long)NEXP * 2 * HDIM * DDIM / 4);
  transpose_wd<<<dim3(DDIM / 64, HDIM / 64, NEXP), 256, 0, stream>>>(wd, wdT);
  gemm1_swiglu<<<dim3(HDIM / 128, TTOK / 256, NEXP), 512, 0, stream>>>(xb, wugb, hid);
  gemm2_down<<<dim3(DDIM / 256, TTOK / 256, NEXP), 512, 0, stream>>>(hid, wdT, out);
}